// Round 22
// baseline (57.814 us; speedup 1.0000x reference)
//
#include <hip/hip_runtime.h>
#include <hip/hip_bf16.h>
#include <math.h>

#define BS 8
#define NPTS 8192
#define NM 32
#define D 512
#define NT (BS*NM)            // 256 masks
#define KC 16                 // K-split factor
#define KCHUNK (NPTS/KC)      // 512 points per block
#define TILES (KCHUNK/32)     // 16 k-tiles of 32
#define DC 8                  // D-chunks
#define DCHUNK (D/DC)         // 64 dims per block (4 waves x 16)
#define NWORDS (NPTS/32)      // 256 uints per mask row
#define K1GRID (BS*KC*DC)     // 1024

#define LOG2E 1.44269504088896f
#define LN2   0.69314718055995f

typedef short short8 __attribute__((ext_vector_type(8)));
typedef float f32x4 __attribute__((ext_vector_type(4)));

// ws layout (floats):
static constexpr size_t OFF_SUMF = 0;                        // [NT][D] (atomic acc, zeroed by kp)
static constexpr size_t OFF_CNTS = OFF_SUMF + (size_t)NT*D;  // [NT]
static constexpr size_t OFF_BITS = OFF_CNTS + NT;            // [NT][NWORDS] uints (256KB)
static constexpr size_t OFF_LOG  = OFF_BITS + (size_t)NT*NWORDS;
static constexpr size_t OFF_RLSE = OFF_LOG + (size_t)NT*NT;
static constexpr size_t OFF_CLSE = OFF_RLSE + NT;
static constexpr size_t OFF_TICK = OFF_CLSE + NT;            // ticket (int)

__device__ __forceinline__ short bf16_rne(float f) {
  return __builtin_bit_cast(short, __float2bfloat16(f));
}

// KP: bit-pack mask (8MB f32 -> 256KB bits), exact popcount counts,
// zero sumf + ticket. Grid: 256 blocks (one per mask).  [R14/R17-proven]
__global__ __launch_bounds__(256) void kp_prep(const float* __restrict__ mpts,
                                               unsigned int* __restrict__ mbits,
                                               float* __restrict__ cnts,
                                               float* __restrict__ sumf,
                                               int* __restrict__ ticket) {
  const int n = blockIdx.x;
  const int t = threadIdx.x;
  if (n == 0 && t == 0) *ticket = 0;
  const float4* mp = (const float4*)(mpts + ((size_t)n << 13) + t * 32);
  unsigned int u = 0;
  #pragma unroll
  for (int q = 0; q < 8; ++q) {
    const float4 v = mp[q];
    u |= (v.x != 0.f ? 1u : 0u) << (q * 4 + 0);
    u |= (v.y != 0.f ? 1u : 0u) << (q * 4 + 1);
    u |= (v.z != 0.f ? 1u : 0u) << (q * 4 + 2);
    u |= (v.w != 0.f ? 1u : 0u) << (q * 4 + 3);
  }
  mbits[n * NWORDS + t] = u;
  ((float2*)(sumf + ((size_t)n << 9)))[t] = make_float2(0.f, 0.f);
  int c = __popc(u);
  #pragma unroll
  for (int o = 32; o > 0; o >>= 1) c += __shfl_down(c, o, 64);
  __shared__ int red[4];
  if ((t & 63) == 0) red[t >> 6] = c;
  __syncthreads();
  if (t == 0) cnts[n] = (float)(red[0] + red[1] + red[2] + red[3]);
}

// K1: masked-sum einsum via bf16 MFMA, B direct-to-register, bitmask A,
// KC=16, 2-deep reg prefetch, XCD swizzle [R21-proven best].
// SINGLE CHANGE vs R21: B-loads are NON-TEMPORAL (nt flag) — the B stream
// touches 16 distinct 128B lines per instr with zero L1 reuse; nt skips the
// L1 allocate/evict so the scatter stops thrashing the 256-line L1.
// Grid: 1024 blocks -> 16 waves/CU.
__global__ __launch_bounds__(256, 4) void k1_mfma(const float* __restrict__ net,
                                                  const unsigned int* __restrict__ mbits,
                                                  float* __restrict__ sumf) {
  const int bx = blockIdx.x;
  const int wid = (bx & 7) * (K1GRID / 8) + (bx >> 3);   // XCD-aware swizzle
  const int dc = wid & 7;
  const int kc = (wid >> 3) & 15;
  const int b  = wid >> 7;
  const int w    = threadIdx.x >> 6;
  const int lane = threadIdx.x & 63;
  const int lhi = lane >> 4, llo = lane & 15;
  const int k0 = kc * KCHUNK;
  const int d0 = dc * DCHUNK + w * 16;

  const unsigned int* r0 = mbits + (size_t)(b * NM + llo) * NWORDS + kc * TILES;
  const unsigned int* r1 = r0 + (size_t)16 * NWORDS;

  const float* np_ = net + (((size_t)(b * NPTS + k0 + lhi * 8)) << 9) + d0 + llo;

  f32x4 acc0 = {0.f, 0.f, 0.f, 0.f};
  f32x4 acc1 = {0.f, 0.f, 0.f, 0.f};
  const int sh = lhi * 8;

  float bv0[8], bv1[8];

  // prologue: tile 0 -> bv0
  #pragma unroll
  for (int j = 0; j < 8; ++j)
    bv0[j] = __builtin_nontemporal_load(np_ + ((size_t)j << 9));
  np_ += (size_t)32 << 9;

  #pragma unroll
  for (int tp = 0; tp < TILES / 2; ++tp) {
    // --- even tile t = 2tp: prefetch t+1 into bv1, consume bv0 ---
    {
      const int t = 2 * tp;
      const unsigned int u0 = r0[t];
      const unsigned int u1 = r1[t];
      if (t + 1 < TILES) {
        #pragma unroll
        for (int j = 0; j < 8; ++j)
          bv1[j] = __builtin_nontemporal_load(np_ + ((size_t)j << 9));
        np_ += (size_t)32 << 9;
      }
      short8 bf, a0f, a1f;
      #pragma unroll
      for (int j = 0; j < 8; ++j) bf[j] = bf16_rne(bv0[j]);
      const unsigned int b0 = (u0 >> sh) & 0xffu;
      const unsigned int b1 = (u1 >> sh) & 0xffu;
      #pragma unroll
      for (int j = 0; j < 8; ++j) {
        a0f[j] = (short)(-(int)((b0 >> j) & 1u) & 0x3F80);
        a1f[j] = (short)(-(int)((b1 >> j) & 1u) & 0x3F80);
      }
      acc0 = __builtin_amdgcn_mfma_f32_16x16x32_bf16(a0f, bf, acc0, 0, 0, 0);
      acc1 = __builtin_amdgcn_mfma_f32_16x16x32_bf16(a1f, bf, acc1, 0, 0, 0);
    }
    // --- odd tile t = 2tp+1: prefetch t+1 into bv0, consume bv1 ---
    {
      const int t = 2 * tp + 1;
      const unsigned int u0 = r0[t];
      const unsigned int u1 = r1[t];
      if (t + 1 < TILES) {
        #pragma unroll
        for (int j = 0; j < 8; ++j)
          bv0[j] = __builtin_nontemporal_load(np_ + ((size_t)j << 9));
        np_ += (size_t)32 << 9;
      }
      short8 bf, a0f, a1f;
      #pragma unroll
      for (int j = 0; j < 8; ++j) bf[j] = bf16_rne(bv1[j]);
      const unsigned int b0 = (u0 >> sh) & 0xffu;
      const unsigned int b1 = (u1 >> sh) & 0xffu;
      #pragma unroll
      for (int j = 0; j < 8; ++j) {
        a0f[j] = (short)(-(int)((b0 >> j) & 1u) & 0x3F80);
        a1f[j] = (short)(-(int)((b1 >> j) & 1u) & 0x3F80);
      }
      acc0 = __builtin_amdgcn_mfma_f32_16x16x32_bf16(a0f, bf, acc0, 0, 0, 0);
      acc1 = __builtin_amdgcn_mfma_f32_16x16x32_bf16(a1f, bf, acc1, 0, 0, 0);
    }
  }

  // C/D: col = llo (d), row = lhi*4 + j (m) [m89-verified]; atomic accumulate
  float* sp = sumf + (((size_t)(b * NM)) << 9) + d0 + llo;
  #pragma unroll
  for (int j = 0; j < 4; ++j) {
    atomicAdd(sp + ((size_t)(lhi * 4 + j) << 9),      acc0[j]);
    atomicAdd(sp + ((size_t)(16 + lhi * 4 + j) << 9), acc1[j]);
  }
}

// K2: logits = exp(lsc) * (embs @ sumf^T) * inv_cnt[col], bf16 MFMA.
// Grid: 256 blocks x 2 waves; wave h does K-half h, LDS combine, wave 0 writes.
__global__ __launch_bounds__(128) void k2_logits(const float* __restrict__ embs,
                                                 const float* __restrict__ sumf,
                                                 const float* __restrict__ cnts,
                                                 const float* __restrict__ lsc,
                                                 float* __restrict__ logits) {
  const int h = threadIdx.x >> 6;           // K-half
  const int lane = threadIdx.x & 63;
  const int wt = blockIdx.x;                // 0..255
  const int ti = wt >> 4, tj = wt & 15;
  const int lhi = lane >> 4, llo = lane & 15;

  const float* ea = embs + (((size_t)(ti * 16 + llo)) << 9) + h * 256 + lhi * 8;
  const float* sv = sumf + (((size_t)(tj * 16 + llo)) << 9) + h * 256 + lhi * 8;
  f32x4 acc = {0.f, 0.f, 0.f, 0.f};
  #pragma unroll
  for (int kk = 0; kk < 8; ++kk) {
    const float4 e0 = *(const float4*)(ea);
    const float4 e1 = *(const float4*)(ea + 4);
    const float4 v0 = *(const float4*)(sv);
    const float4 v1 = *(const float4*)(sv + 4);
    const float ev[8] = {e0.x, e0.y, e0.z, e0.w, e1.x, e1.y, e1.z, e1.w};
    const float vv[8] = {v0.x, v0.y, v0.z, v0.w, v1.x, v1.y, v1.z, v1.w};
    short8 ef, vf;
    #pragma unroll
    for (int j = 0; j < 8; ++j) { ef[j] = bf16_rne(ev[j]); vf[j] = bf16_rne(vv[j]); }
    acc = __builtin_amdgcn_mfma_f32_16x16x32_bf16(ef, vf, acc, 0, 0, 0);
    ea += 32; sv += 32;
  }

  __shared__ float part[64 * 4];
  if (h == 1) *(float4*)(&part[lane * 4]) = make_float4(acc[0], acc[1], acc[2], acc[3]);
  __syncthreads();
  if (h == 0) {
    const float4 p = *(const float4*)(&part[lane * 4]);
    const float scale = expf(lsc[0]);
    const float invc = scale / (cnts[tj * 16 + llo] + 1e-12f);
    float* lp = logits + (size_t)(ti * 16) * NT + tj * 16 + llo;
    lp[(size_t)(lhi * 4 + 0) * NT] = (acc[0] + p.x) * invc;
    lp[(size_t)(lhi * 4 + 1) * NT] = (acc[1] + p.y) * invc;
    lp[(size_t)(lhi * 4 + 2) * NT] = (acc[2] + p.z) * invc;
    lp[(size_t)(lhi * 4 + 3) * NT] = (acc[3] + p.w) * invc;
  }
}

// K3: LSEs (base-2), blocks 0..15 col-LSE, 16..31 row-LSE; LAST block (ticket)
// also computes the final nonzero-avg scalar (fused k4).
__global__ __launch_bounds__(256) void k3_lse(const float* __restrict__ logits,
                                              float* __restrict__ rowlse,
                                              float* __restrict__ clse,
                                              const float* __restrict__ cnts,
                                              int* __restrict__ ticket,
                                              float* __restrict__ out) {
  const int g = blockIdx.x;
  const int r = threadIdx.x >> 4;
  const int c = threadIdx.x & 15;
  __shared__ float red[16][17];
  if (g < 16) {
    const int col = g * 16 + c;
    float mx = -1e30f;
    #pragma unroll 4
    for (int kk = 0; kk < 16; ++kk)
      mx = fmaxf(mx, logits[(size_t)(kk * 16 + r) * NT + col]);
    red[r][c] = mx; __syncthreads();
    for (int st = 8; st; st >>= 1) { if (r < st) red[r][c] = fmaxf(red[r][c], red[r + st][c]); __syncthreads(); }
    const float mx2 = red[0][c] * LOG2E; __syncthreads();
    float s = 0.f;
    #pragma unroll 4
    for (int kk = 0; kk < 16; ++kk)
      s += exp2f(logits[(size_t)(kk * 16 + r) * NT + col] * LOG2E - mx2);
    red[r][c] = s; __syncthreads();
    for (int st = 8; st; st >>= 1) { if (r < st) red[r][c] += red[r + st][c]; __syncthreads(); }
    if (r == 0) clse[col] = (mx2 + log2f(red[0][c])) * LN2;
  } else {
    const int row = (g - 16) * 16 + r;
    float mx = -1e30f;
    #pragma unroll 4
    for (int kk = 0; kk < 16; ++kk)
      mx = fmaxf(mx, logits[(size_t)row * NT + kk * 16 + c]);
    #pragma unroll
    for (int o = 8; o; o >>= 1) mx = fmaxf(mx, __shfl_xor(mx, o, 64));
    const float mx2 = mx * LOG2E;
    float s = 0.f;
    #pragma unroll 4
    for (int kk = 0; kk < 16; ++kk)
      s += exp2f(logits[(size_t)row * NT + kk * 16 + c] * LOG2E - mx2);
    #pragma unroll
    for (int o = 8; o; o >>= 1) s += __shfl_xor(s, o, 64);
    if (c == 0) rowlse[row] = (mx2 + log2f(s)) * LN2;
  }

  // --- fused final reduction: last block to finish does k4's work ---
  __shared__ int slast;
  __syncthreads();
  if (threadIdx.x == 0) {
    __threadfence();                       // make this block's LSE writes visible
    slast = (atomicAdd(ticket, 1) == 31);  // device-scope
  }
  __syncthreads();
  if (!slast) return;
  __threadfence();                         // acquire: see all blocks' writes

  const int i = threadIdx.x;
  const float diag = logits[(size_t)i * NT + i];
  const bool valid = cnts[i] > 0.f;
  const float tl = valid ? (rowlse[i] - diag) : 0.f;
  const float pl = valid ? (clse[i] - diag) : 0.f;

  __shared__ float fred[4][256];
  fred[0][i] = tl;
  fred[1][i] = (tl > 0.f) ? 1.f : 0.f;
  fred[2][i] = pl;
  fred[3][i] = (pl > 0.f) ? 1.f : 0.f;
  __syncthreads();
  for (int st = 128; st > 0; st >>= 1) {
    if (i < st) {
      fred[0][i] += fred[0][i + st];
      fred[1][i] += fred[1][i + st];
      fred[2][i] += fred[2][i + st];
      fred[3][i] += fred[3][i + st];
    }
    __syncthreads();
  }
  if (i == 0) {
    const float a1 = (fred[1][0] > 0.f) ? fred[0][0] / fmaxf(fred[1][0], 1.f) : 0.f;
    const float a2 = (fred[3][0] > 0.f) ? fred[2][0] / fmaxf(fred[3][0], 1.f) : 0.f;
    out[0] = 0.5f * (a1 + a2);
  }
}

extern "C" void kernel_launch(void* const* d_in, const int* in_sizes, int n_in,
                              void* d_out, int out_size, void* d_ws, size_t ws_size,
                              hipStream_t stream) {
  const float* net  = (const float*)d_in[0];
  const float* embs = (const float*)d_in[1];
  const float* mpts = (const float*)d_in[2];
  const float* lsc  = (const float*)d_in[3];

  float* ws     = (float*)d_ws;
  float* sumf   = ws + OFF_SUMF;
  float* cnts   = ws + OFF_CNTS;
  unsigned int* mbits = (unsigned int*)(ws + OFF_BITS);
  float* logits = ws + OFF_LOG;
  float* rowlse = ws + OFF_RLSE;
  float* clse   = ws + OFF_CLSE;
  int*   ticket = (int*)(ws + OFF_TICK);
  float* outp   = (float*)d_out;

  kp_prep<<<dim3(NT), dim3(256), 0, stream>>>(mpts, mbits, cnts, sumf, ticket);
  k1_mfma<<<dim3(K1GRID), dim3(256), 0, stream>>>(net, mbits, sumf);
  k2_logits<<<dim3(NT), dim3(128), 0, stream>>>(embs, sumf, cnts, lsc, logits);
  k3_lse<<<dim3(32), dim3(256), 0, stream>>>(logits, rowlse, clse, cnts, ticket, outp);
}

// Round 23
// 47.447 us; speedup vs baseline: 1.2185x; 1.2185x over previous
//
#include <hip/hip_runtime.h>
#include <hip/hip_bf16.h>
#include <math.h>

#define BS 8
#define NPTS 8192
#define NM 32
#define D 512
#define NT (BS*NM)            // 256 masks
#define KC 16                 // K-split factor
#define KCHUNK (NPTS/KC)      // 512 points per block
#define TILES (KCHUNK/32)     // 16 k-tiles of 32
#define DC 8                  // D-chunks
#define DCHUNK (D/DC)         // 64 dims per block (4 waves x 16)
#define NWORDS (NPTS/32)      // 256 uints per mask row
#define K1GRID (BS*KC*DC)     // 1024

#define LOG2E 1.44269504088896f
#define LN2   0.69314718055995f

typedef short short8 __attribute__((ext_vector_type(8)));
typedef float f32x4 __attribute__((ext_vector_type(4)));

// ws layout (floats):
static constexpr size_t OFF_SUMF = 0;                        // [NT][D] (atomic acc, zeroed by kp)
static constexpr size_t OFF_CNTS = OFF_SUMF + (size_t)NT*D;  // [NT]
static constexpr size_t OFF_BITS = OFF_CNTS + NT;            // [NT][NWORDS] uints (256KB)
static constexpr size_t OFF_LOG  = OFF_BITS + (size_t)NT*NWORDS;
static constexpr size_t OFF_RLSE = OFF_LOG + (size_t)NT*NT;
static constexpr size_t OFF_CLSE = OFF_RLSE + NT;
static constexpr size_t OFF_TICK = OFF_CLSE + NT;            // ticket (int)

__device__ __forceinline__ short bf16_rne(float f) {
  return __builtin_bit_cast(short, __float2bfloat16(f));
}

// KP: bit-pack mask (8MB f32 -> 256KB bits), exact popcount counts,
// zero sumf + ticket. Grid: 256 blocks (one per mask).  [R14/R17-proven]
__global__ __launch_bounds__(256) void kp_prep(const float* __restrict__ mpts,
                                               unsigned int* __restrict__ mbits,
                                               float* __restrict__ cnts,
                                               float* __restrict__ sumf,
                                               int* __restrict__ ticket) {
  const int n = blockIdx.x;
  const int t = threadIdx.x;
  if (n == 0 && t == 0) *ticket = 0;
  const float4* mp = (const float4*)(mpts + ((size_t)n << 13) + t * 32);
  unsigned int u = 0;
  #pragma unroll
  for (int q = 0; q < 8; ++q) {
    const float4 v = mp[q];
    u |= (v.x != 0.f ? 1u : 0u) << (q * 4 + 0);
    u |= (v.y != 0.f ? 1u : 0u) << (q * 4 + 1);
    u |= (v.z != 0.f ? 1u : 0u) << (q * 4 + 2);
    u |= (v.w != 0.f ? 1u : 0u) << (q * 4 + 3);
  }
  mbits[n * NWORDS + t] = u;
  ((float2*)(sumf + ((size_t)n << 9)))[t] = make_float2(0.f, 0.f);
  int c = __popc(u);
  #pragma unroll
  for (int o = 32; o > 0; o >>= 1) c += __shfl_down(c, o, 64);
  __shared__ int red[4];
  if ((t & 63) == 0) red[t >> 6] = c;
  __syncthreads();
  if (t == 0) cnts[n] = (float)(red[0] + red[1] + red[2] + red[3]);
}

// K1: masked-sum einsum via bf16 MFMA, B direct-to-register, bitmask A,
// KC=16, 2-deep reg prefetch, XCD-aware bijective swizzle.  [R21-proven best]
// Grid: 1024 blocks -> 16 waves/CU.
__global__ __launch_bounds__(256, 4) void k1_mfma(const float* __restrict__ net,
                                                  const unsigned int* __restrict__ mbits,
                                                  float* __restrict__ sumf) {
  const int bx = blockIdx.x;
  const int wid = (bx & 7) * (K1GRID / 8) + (bx >> 3);   // XCD-aware swizzle
  const int dc = wid & 7;
  const int kc = (wid >> 3) & 15;
  const int b  = wid >> 7;
  const int w    = threadIdx.x >> 6;
  const int lane = threadIdx.x & 63;
  const int lhi = lane >> 4, llo = lane & 15;
  const int k0 = kc * KCHUNK;
  const int d0 = dc * DCHUNK + w * 16;

  const unsigned int* r0 = mbits + (size_t)(b * NM + llo) * NWORDS + kc * TILES;
  const unsigned int* r1 = r0 + (size_t)16 * NWORDS;

  const float* np_ = net + (((size_t)(b * NPTS + k0 + lhi * 8)) << 9) + d0 + llo;

  f32x4 acc0 = {0.f, 0.f, 0.f, 0.f};
  f32x4 acc1 = {0.f, 0.f, 0.f, 0.f};
  const int sh = lhi * 8;

  float bv0[8], bv1[8];

  // prologue: tile 0 -> bv0
  #pragma unroll
  for (int j = 0; j < 8; ++j) bv0[j] = np_[(size_t)j << 9];
  np_ += (size_t)32 << 9;

  #pragma unroll
  for (int tp = 0; tp < TILES / 2; ++tp) {
    // --- even tile t = 2tp: prefetch t+1 into bv1, consume bv0 ---
    {
      const int t = 2 * tp;
      const unsigned int u0 = r0[t];
      const unsigned int u1 = r1[t];
      if (t + 1 < TILES) {
        #pragma unroll
        for (int j = 0; j < 8; ++j) bv1[j] = np_[(size_t)j << 9];
        np_ += (size_t)32 << 9;
      }
      short8 bf, a0f, a1f;
      #pragma unroll
      for (int j = 0; j < 8; ++j) bf[j] = bf16_rne(bv0[j]);
      const unsigned int b0 = (u0 >> sh) & 0xffu;
      const unsigned int b1 = (u1 >> sh) & 0xffu;
      #pragma unroll
      for (int j = 0; j < 8; ++j) {
        a0f[j] = (short)(-(int)((b0 >> j) & 1u) & 0x3F80);
        a1f[j] = (short)(-(int)((b1 >> j) & 1u) & 0x3F80);
      }
      acc0 = __builtin_amdgcn_mfma_f32_16x16x32_bf16(a0f, bf, acc0, 0, 0, 0);
      acc1 = __builtin_amdgcn_mfma_f32_16x16x32_bf16(a1f, bf, acc1, 0, 0, 0);
    }
    // --- odd tile t = 2tp+1: prefetch t+1 into bv0, consume bv1 ---
    {
      const int t = 2 * tp + 1;
      const unsigned int u0 = r0[t];
      const unsigned int u1 = r1[t];
      if (t + 1 < TILES) {
        #pragma unroll
        for (int j = 0; j < 8; ++j) bv0[j] = np_[(size_t)j << 9];
        np_ += (size_t)32 << 9;
      }
      short8 bf, a0f, a1f;
      #pragma unroll
      for (int j = 0; j < 8; ++j) bf[j] = bf16_rne(bv1[j]);
      const unsigned int b0 = (u0 >> sh) & 0xffu;
      const unsigned int b1 = (u1 >> sh) & 0xffu;
      #pragma unroll
      for (int j = 0; j < 8; ++j) {
        a0f[j] = (short)(-(int)((b0 >> j) & 1u) & 0x3F80);
        a1f[j] = (short)(-(int)((b1 >> j) & 1u) & 0x3F80);
      }
      acc0 = __builtin_amdgcn_mfma_f32_16x16x32_bf16(a0f, bf, acc0, 0, 0, 0);
      acc1 = __builtin_amdgcn_mfma_f32_16x16x32_bf16(a1f, bf, acc1, 0, 0, 0);
    }
  }

  // C/D: col = llo (d), row = lhi*4 + j (m) [m89-verified]; atomic accumulate
  float* sp = sumf + (((size_t)(b * NM)) << 9) + d0 + llo;
  #pragma unroll
  for (int j = 0; j < 4; ++j) {
    atomicAdd(sp + ((size_t)(lhi * 4 + j) << 9),      acc0[j]);
    atomicAdd(sp + ((size_t)(16 + lhi * 4 + j) << 9), acc1[j]);
  }
}

// K2: logits = exp(lsc) * (embs @ sumf^T) * inv_cnt[col], bf16 MFMA.
// Grid: 256 blocks x 2 waves; wave h does K-half h, LDS combine, wave 0 writes.
__global__ __launch_bounds__(128) void k2_logits(const float* __restrict__ embs,
                                                 const float* __restrict__ sumf,
                                                 const float* __restrict__ cnts,
                                                 const float* __restrict__ lsc,
                                                 float* __restrict__ logits) {
  const int h = threadIdx.x >> 6;           // K-half
  const int lane = threadIdx.x & 63;
  const int wt = blockIdx.x;                // 0..255
  const int ti = wt >> 4, tj = wt & 15;
  const int lhi = lane >> 4, llo = lane & 15;

  const float* ea = embs + (((size_t)(ti * 16 + llo)) << 9) + h * 256 + lhi * 8;
  const float* sv = sumf + (((size_t)(tj * 16 + llo)) << 9) + h * 256 + lhi * 8;
  f32x4 acc = {0.f, 0.f, 0.f, 0.f};
  #pragma unroll
  for (int kk = 0; kk < 8; ++kk) {
    const float4 e0 = *(const float4*)(ea);
    const float4 e1 = *(const float4*)(ea + 4);
    const float4 v0 = *(const float4*)(sv);
    const float4 v1 = *(const float4*)(sv + 4);
    const float ev[8] = {e0.x, e0.y, e0.z, e0.w, e1.x, e1.y, e1.z, e1.w};
    const float vv[8] = {v0.x, v0.y, v0.z, v0.w, v1.x, v1.y, v1.z, v1.w};
    short8 ef, vf;
    #pragma unroll
    for (int j = 0; j < 8; ++j) { ef[j] = bf16_rne(ev[j]); vf[j] = bf16_rne(vv[j]); }
    acc = __builtin_amdgcn_mfma_f32_16x16x32_bf16(ef, vf, acc, 0, 0, 0);
    ea += 32; sv += 32;
  }

  __shared__ float part[64 * 4];
  if (h == 1) *(float4*)(&part[lane * 4]) = make_float4(acc[0], acc[1], acc[2], acc[3]);
  __syncthreads();
  if (h == 0) {
    const float4 p = *(const float4*)(&part[lane * 4]);
    const float scale = expf(lsc[0]);
    const float invc = scale / (cnts[tj * 16 + llo] + 1e-12f);
    float* lp = logits + (size_t)(ti * 16) * NT + tj * 16 + llo;
    lp[(size_t)(lhi * 4 + 0) * NT] = (acc[0] + p.x) * invc;
    lp[(size_t)(lhi * 4 + 1) * NT] = (acc[1] + p.y) * invc;
    lp[(size_t)(lhi * 4 + 2) * NT] = (acc[2] + p.z) * invc;
    lp[(size_t)(lhi * 4 + 3) * NT] = (acc[3] + p.w) * invc;
  }
}

// K3: LSEs (base-2), blocks 0..15 col-LSE, 16..31 row-LSE; LAST block (ticket)
// also computes the final nonzero-avg scalar (fused k4).
__global__ __launch_bounds__(256) void k3_lse(const float* __restrict__ logits,
                                              float* __restrict__ rowlse,
                                              float* __restrict__ clse,
                                              const float* __restrict__ cnts,
                                              int* __restrict__ ticket,
                                              float* __restrict__ out) {
  const int g = blockIdx.x;
  const int r = threadIdx.x >> 4;
  const int c = threadIdx.x & 15;
  __shared__ float red[16][17];
  if (g < 16) {
    const int col = g * 16 + c;
    float mx = -1e30f;
    #pragma unroll 4
    for (int kk = 0; kk < 16; ++kk)
      mx = fmaxf(mx, logits[(size_t)(kk * 16 + r) * NT + col]);
    red[r][c] = mx; __syncthreads();
    for (int st = 8; st; st >>= 1) { if (r < st) red[r][c] = fmaxf(red[r][c], red[r + st][c]); __syncthreads(); }
    const float mx2 = red[0][c] * LOG2E; __syncthreads();
    float s = 0.f;
    #pragma unroll 4
    for (int kk = 0; kk < 16; ++kk)
      s += exp2f(logits[(size_t)(kk * 16 + r) * NT + col] * LOG2E - mx2);
    red[r][c] = s; __syncthreads();
    for (int st = 8; st; st >>= 1) { if (r < st) red[r][c] += red[r + st][c]; __syncthreads(); }
    if (r == 0) clse[col] = (mx2 + log2f(red[0][c])) * LN2;
  } else {
    const int row = (g - 16) * 16 + r;
    float mx = -1e30f;
    #pragma unroll 4
    for (int kk = 0; kk < 16; ++kk)
      mx = fmaxf(mx, logits[(size_t)row * NT + kk * 16 + c]);
    #pragma unroll
    for (int o = 8; o; o >>= 1) mx = fmaxf(mx, __shfl_xor(mx, o, 64));
    const float mx2 = mx * LOG2E;
    float s = 0.f;
    #pragma unroll 4
    for (int kk = 0; kk < 16; ++kk)
      s += exp2f(logits[(size_t)row * NT + kk * 16 + c] * LOG2E - mx2);
    #pragma unroll
    for (int o = 8; o; o >>= 1) s += __shfl_xor(s, o, 64);
    if (c == 0) rowlse[row] = (mx2 + log2f(s)) * LN2;
  }

  // --- fused final reduction: last block to finish does k4's work ---
  __shared__ int slast;
  __syncthreads();
  if (threadIdx.x == 0) {
    __threadfence();                       // make this block's LSE writes visible
    slast = (atomicAdd(ticket, 1) == 31);  // device-scope
  }
  __syncthreads();
  if (!slast) return;
  __threadfence();                         // acquire: see all blocks' writes

  const int i = threadIdx.x;
  const float diag = logits[(size_t)i * NT + i];
  const bool valid = cnts[i] > 0.f;
  const float tl = valid ? (rowlse[i] - diag) : 0.f;
  const float pl = valid ? (clse[i] - diag) : 0.f;

  __shared__ float fred[4][256];
  fred[0][i] = tl;
  fred[1][i] = (tl > 0.f) ? 1.f : 0.f;
  fred[2][i] = pl;
  fred[3][i] = (pl > 0.f) ? 1.f : 0.f;
  __syncthreads();
  for (int st = 128; st > 0; st >>= 1) {
    if (i < st) {
      fred[0][i] += fred[0][i + st];
      fred[1][i] += fred[1][i + st];
      fred[2][i] += fred[2][i + st];
      fred[3][i] += fred[3][i + st];
    }
    __syncthreads();
  }
  if (i == 0) {
    const float a1 = (fred[1][0] > 0.f) ? fred[0][0] / fmaxf(fred[1][0], 1.f) : 0.f;
    const float a2 = (fred[3][0] > 0.f) ? fred[2][0] / fmaxf(fred[3][0], 1.f) : 0.f;
    out[0] = 0.5f * (a1 + a2);
  }
}

extern "C" void kernel_launch(void* const* d_in, const int* in_sizes, int n_in,
                              void* d_out, int out_size, void* d_ws, size_t ws_size,
                              hipStream_t stream) {
  const float* net  = (const float*)d_in[0];
  const float* embs = (const float*)d_in[1];
  const float* mpts = (const float*)d_in[2];
  const float* lsc  = (const float*)d_in[3];

  float* ws     = (float*)d_ws;
  float* sumf   = ws + OFF_SUMF;
  float* cnts   = ws + OFF_CNTS;
  unsigned int* mbits = (unsigned int*)(ws + OFF_BITS);
  float* logits = ws + OFF_LOG;
  float* rowlse = ws + OFF_RLSE;
  float* clse   = ws + OFF_CLSE;
  int*   ticket = (int*)(ws + OFF_TICK);
  float* outp   = (float*)d_out;

  kp_prep<<<dim3(NT), dim3(256), 0, stream>>>(mpts, mbits, cnts, sumf, ticket);
  k1_mfma<<<dim3(K1GRID), dim3(256), 0, stream>>>(net, mbits, sumf);
  k2_logits<<<dim3(NT), dim3(128), 0, stream>>>(embs, sumf, cnts, lsc, logits);
  k3_lse<<<dim3(32), dim3(256), 0, stream>>>(logits, rowlse, clse, cnts, ticket, outp);
}